// Round 3
// baseline (210.505 us; speedup 1.0000x reference)
//
#include <hip/hip_runtime.h>
#include <math.h>

namespace {

constexpr int kRows = 4096;
constexpr int kNF   = 65;
constexpr int kNE   = 256;
constexpr int kNH   = 8;
constexpr int kNC   = 64;                  // kNF - 1 fields used
constexpr int kXRow = kNF * kNE;           // 16640 floats per x row
constexpr int kORow = (kNF + kNH) * kNE;   // 18688 floats per out row

// w2[h*32+d] = sum_k bw[h,d,k] * query[h,k]
__global__ __launch_bounds__(256) void w2_precompute(
    const float* __restrict__ bw, const float* __restrict__ query,
    float* __restrict__ w2) {
  const int t = threadIdx.x;         // t = h*32 + d
  const int h = t >> 5;
  const float4* __restrict__ b4 = reinterpret_cast<const float4*>(bw) + (size_t)t * 64;
  const float4* __restrict__ q4 = reinterpret_cast<const float4*>(query) + (size_t)h * 64;
  float acc = 0.f;
#pragma unroll 8
  for (int k = 0; k < 64; ++k) {
    const float4 b = b4[k];
    const float4 q = q4[k];
    acc += b.x * q.x + b.y * q.y + b.z * q.z + b.w * q.w;
  }
  w2[t] = acc;
}

// One block per row. x is read from global EXACTLY ONCE, fully coalesced:
// thread (wv,lane) keeps 16 fields' e-quad in registers (kreg). att is fused
// into the copy pass (dot + 8-lane shfl reduce). Phase C computes per-wave
// partial x_cross from registers, reduced across waves through LDS.
// LDS ~39 KB -> 4 blocks/CU co-resident.
__global__ __launch_bounds__(256, 4) void fused_row(
    const float* __restrict__ x, const float* __restrict__ w2g,
    const float* __restrict__ vals, float* __restrict__ out) {
  __shared__ float w2s[kNE];            // 1 KB
  __shared__ float vls[kNH * kNC];      // 2 KB
  __shared__ float att_t[kNC * kNH];    // [c][h], 2 KB
  __shared__ float cw[kNC * kNH];       // [c][h], 2 KB
  __shared__ float part[4 * kNH * kNE]; // [wv][h][e], 32 KB

  const int tid  = threadIdx.x;
  const int wv   = tid >> 6;
  const int lane = tid & 63;
  const int r    = blockIdx.x;

  w2s[tid]       = w2g[tid];
  vls[tid]       = vals[tid];
  vls[tid + 256] = vals[tid + 256];
  __syncthreads();

  const float* __restrict__ xrow = x + (size_t)r * kXRow;
  float* __restrict__ orow       = out + (size_t)r * kORow;
  const float4* __restrict__ x4  = reinterpret_cast<const float4*>(xrow);
  float4* __restrict__ o4        = reinterpret_cast<float4*>(orow);

  // ---- phase A: single coalesced read of the row; copy -> out; keys -> regs;
  //      att[c][h] fused (dot + 3-shfl 8-lane reduce). Wave wv owns fields
  //      f = wv + 4j (j=0..15); wave 0 additionally owns f=64 (slot j=0,
  //      since its j=0 slot is field 0 which is not a key).
  float4 kreg[16];
  const float4 wq = reinterpret_cast<const float4*>(w2s)[lane];  // head lane>>3 slice
#pragma unroll
  for (int j = 0; j < 16; ++j) {
    const int f = wv + 4 * j;
    const float4 v = x4[f * 64 + lane];
    o4[f * 64 + lane] = v;
    kreg[j] = v;
    if (f >= 1) {
      float p = v.x * wq.x + v.y * wq.y + v.z * wq.z + v.w * wq.w;
      p += __shfl_xor(p, 1);
      p += __shfl_xor(p, 2);
      p += __shfl_xor(p, 4);
      if ((lane & 7) == 0) att_t[(f - 1) * kNH + (lane >> 3)] = p * 0.03125f;
    }
  }
  if (wv == 0) {   // field 64 -> slot 0
    const float4 v = x4[64 * 64 + lane];
    o4[64 * 64 + lane] = v;
    kreg[0] = v;
    float p = v.x * wq.x + v.y * wq.y + v.z * wq.z + v.w * wq.w;
    p += __shfl_xor(p, 1);
    p += __shfl_xor(p, 2);
    p += __shfl_xor(p, 4);
    if ((lane & 7) == 0) att_t[63 * kNH + (lane >> 3)] = p * 0.03125f;
  }
  __syncthreads();

  // ---- entmax-1.5 bisection (wave 0 only; 8 heads in parallel, lane=h*8+kk) ----
  if (wv == 0) {
    const int h  = lane >> 3;
    const int kk = lane & 7;
    float X[8];
#pragma unroll
    for (int j = 0; j < 8; ++j) X[j] = att_t[(kk * 8 + j) * kNH + h];

    float mx = X[0];
#pragma unroll
    for (int j = 1; j < 8; ++j) mx = fmaxf(mx, X[j]);
    mx = fmaxf(mx, __shfl_xor(mx, 1));
    mx = fmaxf(mx, __shfl_xor(mx, 2));
    mx = fmaxf(mx, __shfl_xor(mx, 4));

    float tau_lo = mx - 1.0f;       // _gp(1, 1.5) = 1
    float dm     = 0.875f;          // 1 - (1/64)^0.5
    float f_lo = 0.f;
#pragma unroll
    for (int j = 0; j < 8; ++j) {
      float t = fmaxf(X[j] - tau_lo, 0.f);
      f_lo += t * t;
    }
    f_lo += __shfl_xor(f_lo, 1);
    f_lo += __shfl_xor(f_lo, 2);
    f_lo += __shfl_xor(f_lo, 4);
    f_lo -= 1.0f;

    float tau_m = tau_lo;
    for (int it = 0; it < 50; ++it) {
      dm *= 0.5f;
      tau_m = tau_lo + dm;
      float fm = 0.f;
#pragma unroll
      for (int j = 0; j < 8; ++j) {
        float t = fmaxf(X[j] - tau_m, 0.f);
        fm += t * t;
      }
      fm += __shfl_xor(fm, 1);
      fm += __shfl_xor(fm, 2);
      fm += __shfl_xor(fm, 4);
      fm -= 1.0f;
      tau_lo = (fm * f_lo >= 0.f) ? tau_m : tau_lo;
      // fp32 fixed point: once tau_lo + dm/2 rounds to tau_lo for every lane,
      // all remaining reference iterations are bitwise no-ops with final
      // tau_m == tau_lo. Exact fp32 semantics preserved (verified rounds 1-2).
      if (__all(tau_lo + dm * 0.5f == tau_lo)) {
        tau_m = tau_lo;
        break;
      }
    }

    float p[8];
    float s = 0.f;
#pragma unroll
    for (int j = 0; j < 8; ++j) {
      float t = fmaxf(X[j] - tau_m, 0.f);
      p[j] = t * t;
      s += p[j];
    }
    s += __shfl_xor(s, 1);
    s += __shfl_xor(s, 2);
    s += __shfl_xor(s, 4);
    const float inv = 1.0f / s;
#pragma unroll
    for (int j = 0; j < 8; ++j) {
      const int c = kk * 8 + j;
      cw[c * kNH + h] = p[j] * inv * vls[h * kNC + c];
    }
  }
  __syncthreads();

  // ---- phase C: per-wave partial x_cross from register keys; 2 passes of
  //      4 heads each to cap VGPR pressure. cw reads are wave-broadcast.
  const float4* __restrict__ cw4 = reinterpret_cast<const float4*>(cw);
  float4* __restrict__ part4     = reinterpret_cast<float4*>(part);
#pragma unroll
  for (int hh = 0; hh < 2; ++hh) {
    float4 acc[4];
#pragma unroll
    for (int i = 0; i < 4; ++i) acc[i] = make_float4(0.f, 0.f, 0.f, 0.f);
#pragma unroll
    for (int j = 0; j < 16; ++j) {
      const int f = (wv == 0) ? (j == 0 ? 64 : 4 * j) : (wv + 4 * j);
      const int c = f - 1;
      const float4 kv = kreg[j];
      const float4 ca = cw4[c * 2 + hh];   // heads 4hh..4hh+3, broadcast
      acc[0].x += ca.x * kv.x; acc[0].y += ca.x * kv.y; acc[0].z += ca.x * kv.z; acc[0].w += ca.x * kv.w;
      acc[1].x += ca.y * kv.x; acc[1].y += ca.y * kv.y; acc[1].z += ca.y * kv.z; acc[1].w += ca.y * kv.w;
      acc[2].x += ca.z * kv.x; acc[2].y += ca.z * kv.y; acc[2].z += ca.z * kv.z; acc[2].w += ca.z * kv.w;
      acc[3].x += ca.w * kv.x; acc[3].y += ca.w * kv.y; acc[3].z += ca.w * kv.z; acc[3].w += ca.w * kv.w;
    }
#pragma unroll
    for (int i = 0; i < 4; ++i) {
      part4[wv * 512 + (hh * 4 + i) * 64 + lane] = acc[i];  // lane-consecutive
    }
  }
  __syncthreads();

  // ---- cross-wave reduce + exp + coalesced store of x_cross ----
#pragma unroll
  for (int o = tid; o < 512; o += 256) {
    float4 s0 = part4[o];
    const float4 s1 = part4[512 + o];
    const float4 s2 = part4[1024 + o];
    const float4 s3 = part4[1536 + o];
    s0.x += s1.x + s2.x + s3.x;
    s0.y += s1.y + s2.y + s3.y;
    s0.z += s1.z + s2.z + s3.z;
    s0.w += s1.w + s2.w + s3.w;
    float4 e;
    e.x = expf(s0.x); e.y = expf(s0.y); e.z = expf(s0.z); e.w = expf(s0.w);
    reinterpret_cast<float4*>(orow + kXRow)[o] = e;
  }
}

}  // namespace

extern "C" void kernel_launch(void* const* d_in, const int* in_sizes, int n_in,
                              void* d_out, int out_size, void* d_ws, size_t ws_size,
                              hipStream_t stream) {
  const float* x     = reinterpret_cast<const float*>(d_in[0]);
  const float* bw    = reinterpret_cast<const float*>(d_in[1]);
  const float* query = reinterpret_cast<const float*>(d_in[2]);
  const float* vals  = reinterpret_cast<const float*>(d_in[3]);
  float* out = reinterpret_cast<float*>(d_out);
  float* w2  = reinterpret_cast<float*>(d_ws);   // 256 floats of scratch

  hipLaunchKernelGGL(w2_precompute, dim3(1), dim3(256), 0, stream, bw, query, w2);
  hipLaunchKernelGGL(fused_row, dim3(kRows), dim3(256), 0, stream, x, w2, vals, out);
}

// Round 4
// 168.229 us; speedup vs baseline: 1.2513x; 1.2513x over previous
//
#include <hip/hip_runtime.h>
#include <math.h>

namespace {

constexpr int kRows = 4096;
constexpr int kNF   = 65;
constexpr int kNE   = 256;
constexpr int kNH   = 8;
constexpr int kNC   = 64;                  // kNF - 1 fields used
constexpr int kXRow = kNF * kNE;           // 16640 floats per x row
constexpr int kORow = (kNF + kNH) * kNE;   // 18688 floats per out row

// w2[h*32+d] = sum_k bw[h,d,k] * query[h,k]
__global__ __launch_bounds__(256) void w2_precompute(
    const float* __restrict__ bw, const float* __restrict__ query,
    float* __restrict__ w2) {
  const int t = threadIdx.x;         // t = h*32 + d
  const int h = t >> 5;
  const float4* __restrict__ b4 = reinterpret_cast<const float4*>(bw) + (size_t)t * 64;
  const float4* __restrict__ q4 = reinterpret_cast<const float4*>(query) + (size_t)h * 64;
  float acc = 0.f;
#pragma unroll 8
  for (int k = 0; k < 64; ++k) {
    const float4 b = b4[k];
    const float4 q = q4[k];
    acc += b.x * q.x + b.y * q.y + b.z * q.z + b.w * q.w;
  }
  w2[t] = acc;
}

// One block per row. x read from global EXACTLY ONCE, coalesced; keys live in
// registers (wave wv owns keys c = wv*16+j, thread holds its e-quad: 16 float4).
// waves_per_eu(4,4) pins the compiler to a 128-VGPR budget (LDS already caps
// at 4 blocks/CU = 4 waves/SIMD) so kreg is NOT spilled (round-3 failure:
// compiler targeted 8 waves/EU -> 64 VGPR -> full scratch spill, +231 MB HBM).
__global__ __attribute__((amdgpu_flat_work_group_size(256, 256),
                          amdgpu_waves_per_eu(4, 4)))
void fused_row(
    const float* __restrict__ x, const float* __restrict__ w2g,
    const float* __restrict__ vals, float* __restrict__ out) {
  __shared__ float w2s[kNE];            // 1 KB
  __shared__ float vls[kNH * kNC];      // 2 KB
  __shared__ float att_t[kNC * 9];      // [c][h], stride 9 kills bank conflict
  __shared__ float cw[kNC * kNH];       // [c][h], 2 KB
  __shared__ float part[4 * kNH * kNE]; // [wv][h][e], 32 KB

  const int tid  = threadIdx.x;
  const int wv   = tid >> 6;
  const int lane = tid & 63;
  const int r    = blockIdx.x;

  w2s[tid]       = w2g[tid];
  vls[tid]       = vals[tid];
  vls[tid + 256] = vals[tid + 256];
  __syncthreads();

  const float* __restrict__ xrow = x + (size_t)r * kXRow;
  float* __restrict__ orow       = out + (size_t)r * kORow;
  const float4* __restrict__ x4  = reinterpret_cast<const float4*>(xrow);
  float4* __restrict__ o4        = reinterpret_cast<float4*>(orow);

  // ---- phase A: single coalesced read; copy -> out; keys -> regs; att fused.
  //      Lane's w2 quad: head h = lane>>3, dims 4*(lane&7)..+3 — matches the
  //      e-quad of its key load; 3-level shfl reduces over lane&7.
  float4 kreg[16];
  const float4 wq = reinterpret_cast<const float4*>(w2s)[lane];
  if (wv == 0) o4[lane] = x4[lane];     // field 0: copy only (not a key)
#pragma unroll
  for (int j = 0; j < 16; ++j) {
    const int c = wv * 16 + j;          // key index; field f = c+1
    const float4 v = x4[(c + 1) * 64 + lane];
    o4[(c + 1) * 64 + lane] = v;
    kreg[j] = v;
    float p = v.x * wq.x + v.y * wq.y + v.z * wq.z + v.w * wq.w;
    p += __shfl_xor(p, 1);
    p += __shfl_xor(p, 2);
    p += __shfl_xor(p, 4);
    if ((lane & 7) == 0) att_t[c * 9 + (lane >> 3)] = p * 0.03125f;
  }
  __syncthreads();

  // ---- entmax-1.5 bisection, run redundantly by ALL waves (identical inputs
  //      and ops -> bitwise-identical results; the cw writes are a benign
  //      identical-value race; each wave reads back its own writes, so no
  //      barrier is needed between entmax and phase C). Removes the round-3
  //      wave0-only serial section + one barrier. lane = h*8+kk, 8 c's/lane.
  {
    const int h  = lane >> 3;
    const int kk = lane & 7;
    float X[8];
#pragma unroll
    for (int j = 0; j < 8; ++j) X[j] = att_t[(kk * 8 + j) * 9 + h];

    float mx = X[0];
#pragma unroll
    for (int j = 1; j < 8; ++j) mx = fmaxf(mx, X[j]);
    mx = fmaxf(mx, __shfl_xor(mx, 1));
    mx = fmaxf(mx, __shfl_xor(mx, 2));
    mx = fmaxf(mx, __shfl_xor(mx, 4));

    float tau_lo = mx - 1.0f;       // _gp(1, 1.5) = 1
    float dm     = 0.875f;          // 1 - (1/64)^0.5
    float f_lo = 0.f;
#pragma unroll
    for (int j = 0; j < 8; ++j) {
      float t = fmaxf(X[j] - tau_lo, 0.f);
      f_lo += t * t;
    }
    f_lo += __shfl_xor(f_lo, 1);
    f_lo += __shfl_xor(f_lo, 2);
    f_lo += __shfl_xor(f_lo, 4);
    f_lo -= 1.0f;

    float tau_m = tau_lo;
    for (int it = 0; it < 50; ++it) {
      dm *= 0.5f;
      tau_m = tau_lo + dm;
      float fm = 0.f;
#pragma unroll
      for (int j = 0; j < 8; ++j) {
        float t = fmaxf(X[j] - tau_m, 0.f);
        fm += t * t;
      }
      fm += __shfl_xor(fm, 1);
      fm += __shfl_xor(fm, 2);
      fm += __shfl_xor(fm, 4);
      fm -= 1.0f;
      tau_lo = (fm * f_lo >= 0.f) ? tau_m : tau_lo;
      // fp32 fixed point: once tau_lo + dm/2 rounds to tau_lo for every lane,
      // all remaining reference iterations are bitwise no-ops with final
      // tau_m == tau_lo. Exact fp32 semantics preserved (verified rounds 1-3).
      if (__all(tau_lo + dm * 0.5f == tau_lo)) {
        tau_m = tau_lo;
        break;
      }
    }

    float p[8];
    float s = 0.f;
#pragma unroll
    for (int j = 0; j < 8; ++j) {
      float t = fmaxf(X[j] - tau_m, 0.f);
      p[j] = t * t;
      s += p[j];
    }
    s += __shfl_xor(s, 1);
    s += __shfl_xor(s, 2);
    s += __shfl_xor(s, 4);
    const float inv = 1.0f / s;
#pragma unroll
    for (int j = 0; j < 8; ++j) {
      const int c = kk * 8 + j;
      cw[c * kNH + h] = p[j] * inv * vls[h * kNC + c];
    }
  }
  // no barrier: each wave reads back only values it wrote itself.

  // ---- phase C: per-wave partial x_cross from register keys; 2 passes of
  //      4 heads to cap VGPR pressure. cw reads are wave-broadcast.
  const float4* __restrict__ cw4 = reinterpret_cast<const float4*>(cw);
  float4* __restrict__ part4     = reinterpret_cast<float4*>(part);
#pragma unroll
  for (int hh = 0; hh < 2; ++hh) {
    float4 acc[4];
#pragma unroll
    for (int i = 0; i < 4; ++i) acc[i] = make_float4(0.f, 0.f, 0.f, 0.f);
#pragma unroll
    for (int j = 0; j < 16; ++j) {
      const float4 kv = kreg[j];
      const float4 ca = cw4[(wv * 16 + j) * 2 + hh];   // broadcast
      acc[0].x += ca.x * kv.x; acc[0].y += ca.x * kv.y; acc[0].z += ca.x * kv.z; acc[0].w += ca.x * kv.w;
      acc[1].x += ca.y * kv.x; acc[1].y += ca.y * kv.y; acc[1].z += ca.y * kv.z; acc[1].w += ca.y * kv.w;
      acc[2].x += ca.z * kv.x; acc[2].y += ca.z * kv.y; acc[2].z += ca.z * kv.z; acc[2].w += ca.z * kv.w;
      acc[3].x += ca.w * kv.x; acc[3].y += ca.w * kv.y; acc[3].z += ca.w * kv.z; acc[3].w += ca.w * kv.w;
    }
#pragma unroll
    for (int i = 0; i < 4; ++i) {
      part4[wv * 512 + (hh * 4 + i) * 64 + lane] = acc[i];  // lane-consecutive
    }
  }
  __syncthreads();

  // ---- cross-wave reduce + exp + coalesced store of x_cross ----
#pragma unroll
  for (int o = tid; o < 512; o += 256) {
    float4 s0 = part4[o];
    const float4 s1 = part4[512 + o];
    const float4 s2 = part4[1024 + o];
    const float4 s3 = part4[1536 + o];
    s0.x += s1.x + s2.x + s3.x;
    s0.y += s1.y + s2.y + s3.y;
    s0.z += s1.z + s2.z + s3.z;
    s0.w += s1.w + s2.w + s3.w;
    float4 e;
    e.x = expf(s0.x); e.y = expf(s0.y); e.z = expf(s0.z); e.w = expf(s0.w);
    reinterpret_cast<float4*>(orow + kXRow)[o] = e;
  }
}

}  // namespace

extern "C" void kernel_launch(void* const* d_in, const int* in_sizes, int n_in,
                              void* d_out, int out_size, void* d_ws, size_t ws_size,
                              hipStream_t stream) {
  const float* x     = reinterpret_cast<const float*>(d_in[0]);
  const float* bw    = reinterpret_cast<const float*>(d_in[1]);
  const float* query = reinterpret_cast<const float*>(d_in[2]);
  const float* vals  = reinterpret_cast<const float*>(d_in[3]);
  float* out = reinterpret_cast<float*>(d_out);
  float* w2  = reinterpret_cast<float*>(d_ws);   // 256 floats of scratch

  hipLaunchKernelGGL(w2_precompute, dim3(1), dim3(256), 0, stream, bw, query, w2);
  hipLaunchKernelGGL(fused_row, dim3(kRows), dim3(256), 0, stream, x, w2, vals, out);
}